// Round 1
// 621.181 us; speedup vs baseline: 1.1838x; 1.1838x over previous
//
#include <hip/hip_runtime.h>

#define HID 128

typedef __attribute__((ext_vector_type(4)))  float f32x4;
typedef __attribute__((ext_vector_type(16))) float f32x16;
typedef __attribute__((ext_vector_type(8)))  short short8;
typedef __attribute__((ext_vector_type(4)))  short short4v;

// packed fp32x2 -> bf16x2 (RNE) in one instruction (T12 recipe; no builtin on gfx950)
static __device__ __forceinline__ unsigned cvt_pk_bf16(float lo, float hi) {
  unsigned r;
  asm("v_cvt_pk_bf16_f32 %0, %1, %2" : "=v"(r) : "v"(lo), "v"(hi));
  return r;
}

// Uc[g][n] = b1[n] + sum_k u[g][k] * W1[384+k][n]   (exact fp32)
__global__ void prep_uc(const float* __restrict__ u, const float* __restrict__ W1,
                        const float* __restrict__ b1, float* __restrict__ Uc) {
  __shared__ float us[HID];
  const int g = blockIdx.x, n = threadIdx.x;
  us[n] = u[g * HID + n];
  __syncthreads();
  float acc = b1[n];
  const float* w = W1 + 3 * HID * HID + n;
  #pragma unroll 8
  for (int k = 0; k < HID; ++k) acc += us[k] * w[k * HID];
  Uc[g * HID + n] = acc;
}

// Block = 4 waves; wave w owns output cols [32w, 32w+32). Tile = 32 edges.
// A (32x384) staged ONCE per block: coop reg-load -> cvt_pk -> bf16 LDS
// (chunk-major [c16][row], row XOR-swizzled -> conflict-free ds_read_b128).
// Prefetch depth 1: tile t+1's global loads issued at top of tile t, written
// to LDS at end of tile t. Raw s_barrier + lgkm-only waits keep them in
// flight across barriers (no vmcnt(0) drain).
__global__ __launch_bounds__(256, 2) void edge_mlp(
    const float* __restrict__ src, const float* __restrict__ dst,
    const float* __restrict__ ea, const int* __restrict__ batch,
    const float* __restrict__ W1, const float* __restrict__ W2,
    const float* __restrict__ b2, const float* __restrict__ Uc,
    float* __restrict__ out, int E, int nTiles) {
  __shared__ __align__(16) short Abuf[2][48 * 32 * 8];  // 2 x 24 KB bf16 A tiles
  __shared__ __align__(16) short hbuf[16 * 32 * 8];     // 8 KB bf16 h tile

  const int tid  = threadIdx.x;
  const int lane = tid & 63;
  const int wave = tid >> 6;
  const int l31  = lane & 31;
  const int kh   = lane >> 5;           // k-half of MFMA fragment
  const int ncol = wave * 32 + l31;
  const int cst  = (tid & 31) * 4;      // this thread's staged column (4 floats)
  const int rb   = tid >> 5;

  if (blockIdx.x >= nTiles) return;

  // stage chunk i (i=0..11): ch = i*256+tid ; array a = ch>>10 ;
  // row r = (i*8 + rb)&31 ; col = cst ; LDS chunk c16 = a*16 + cst/8
  f32x4 stg[12];
  #define STAGE_ISSUE(e0)                                                      \
    _Pragma("unroll")                                                          \
    for (int i = 0; i < 12; ++i) {                                             \
      const int a  = (i * 256 + tid) >> 10;                                    \
      const int r  = (i * 8 + rb) & 31;                                        \
      const int rg = min((e0) + r, E - 1);                                     \
      const float* gp = (a == 0 ? src : (a == 1 ? dst : ea));                  \
      stg[i] = *(const f32x4*)(gp + (long)rg * HID + cst);                     \
    }

  #define STAGE_WRITE(pb)                                                      \
    _Pragma("unroll")                                                          \
    for (int i = 0; i < 12; ++i) {                                             \
      const int a   = (i * 256 + tid) >> 10;                                   \
      const int r   = (i * 8 + rb) & 31;                                       \
      const int c16 = a * 16 + (cst >> 3);                                     \
      const int off = c16 * 256 + ((r ^ (c16 & 7)) << 3) + (cst & 4);          \
      union { unsigned u[2]; short4v s; } wpk;                                 \
      wpk.u[0] = cvt_pk_bf16(stg[i][0], stg[i][1]);                           \
      wpk.u[1] = cvt_pk_bf16(stg[i][2], stg[i][3]);                           \
      *(short4v*)&Abuf[pb][off] = wpk.s;                                       \
    }

  int t = blockIdx.x;
  const int G = gridDim.x;
  int p = 0;

  // ---- prologue: start HBM flow first, then preload weights while it lands
  STAGE_ISSUE(t * 32)

  short8 B1f[24];
  #pragma unroll
  for (int s = 0; s < 24; ++s) {
    const float* pw = W1 + (long)(s * 16 + kh * 8) * HID + ncol;
    union { unsigned u[4]; short8 s8; } r;
    #pragma unroll
    for (int j = 0; j < 4; ++j)
      r.u[j] = cvt_pk_bf16(pw[(long)(2 * j) * HID], pw[(long)(2 * j + 1) * HID]);
    B1f[s] = r.s8;
  }
  short8 B2f[8];
  #pragma unroll
  for (int s = 0; s < 8; ++s) {
    const float* pw = W2 + (long)(s * 16 + kh * 8) * HID + ncol;
    union { unsigned u[4]; short8 s8; } r;
    #pragma unroll
    for (int j = 0; j < 4; ++j)
      r.u[j] = cvt_pk_bf16(pw[(long)(2 * j) * HID], pw[(long)(2 * j + 1) * HID]);
    B2f[s] = r.s8;
  }
  const float b2v = b2[ncol];

  STAGE_WRITE(0)
  asm volatile("s_waitcnt lgkmcnt(0)" ::: "memory");
  __builtin_amdgcn_s_barrier();

  while (true) {
    const int e0 = t * 32;
    const int tn = t + G;
    const bool more = (tn < nTiles);
    if (more) STAGE_ISSUE(tn * 32)      // prefetch next tile (stays in flight)

    // ---- layer 1: [32 x 384] @ [384 x 32] from swizzled LDS ----
    f32x16 acc;
    #pragma unroll
    for (int i = 0; i < 16; ++i) acc[i] = 0.f;
    #pragma unroll
    for (int s = 0; s < 24; ++s) {
      const int c16 = 2 * s + kh;
      const short8 af = *(const short8*)&Abuf[p][c16 * 256 + ((l31 ^ (c16 & 7)) << 3)];
      acc = __builtin_amdgcn_mfma_f32_32x32x16_bf16(af, B1f[s], acc, 0, 0, 0);
    }

    // ---- add per-graph term (batch sorted: fast uniform path) ----
    const int gA = batch[e0];
    const int gB = batch[min(e0 + 31, E - 1)];
    if (gA == gB) {
      const float ucv = Uc[(long)gA * HID + ncol];
      #pragma unroll
      for (int i = 0; i < 16; ++i) acc[i] += ucv;
    } else {
      #pragma unroll
      for (int i = 0; i < 16; ++i) {
        const int crow = (i & 3) + 8 * (i >> 2) + 4 * kh;
        acc[i] += Uc[(long)batch[min(e0 + crow, E - 1)] * HID + ncol];
      }
    }

    // ---- relu + cvt, h -> LDS (chunk-major, swizzled; 2-way max on writes) ----
    const int hc = ncol >> 3;
    const int hs = ncol & 7;
    #pragma unroll
    for (int j = 0; j < 8; ++j) {
      const int i0 = 2 * j;
      const int r0 = (i0 & 3) + 8 * (i0 >> 2) + 4 * kh;   // rows r0, r0+1
      const unsigned pk = cvt_pk_bf16(fmaxf(acc[i0], 0.f), fmaxf(acc[i0 + 1], 0.f));
      hbuf[hc * 256 + ((r0 ^ (hc & 7)) << 3) + hs]       = (short)(pk & 0xffffu);
      hbuf[hc * 256 + (((r0 + 1) ^ (hc & 7)) << 3) + hs] = (short)(pk >> 16);
    }

    // mid barrier: drain LDS writes only — prefetch loads stay in flight
    asm volatile("s_waitcnt lgkmcnt(0)" ::: "memory");
    __builtin_amdgcn_s_barrier();

    // ---- layer 2: [32 x 128] @ [128 x 32] ----
    f32x16 o;
    #pragma unroll
    for (int i = 0; i < 16; ++i) o[i] = 0.f;
    #pragma unroll
    for (int s = 0; s < 8; ++s) {
      const int c16 = 2 * s + kh;
      const short8 hf = *(const short8*)&hbuf[c16 * 256 + ((l31 ^ (c16 & 7)) << 3)];
      o = __builtin_amdgcn_mfma_f32_32x32x16_bf16(hf, B2f[s], o, 0, 0, 0);
    }

    // ---- epilogue: + b2, store fp32 ----
    #pragma unroll
    for (int i = 0; i < 16; ++i) {
      const int crow = (i & 3) + 8 * (i >> 2) + 4 * kh;
      const int e = e0 + crow;
      if (e < E) out[(long)e * HID + ncol] = o[i] + b2v;
    }

    if (!more) break;
    STAGE_WRITE(p ^ 1)                  // waits the prefetch (vmcnt via uses), cvt, LDS
    asm volatile("s_waitcnt lgkmcnt(0)" ::: "memory");
    __builtin_amdgcn_s_barrier();       // A(t+1) visible to all; h reads long done
    p ^= 1;
    t = tn;
  }
  #undef STAGE_ISSUE
  #undef STAGE_WRITE
}

extern "C" void kernel_launch(void* const* d_in, const int* in_sizes, int n_in,
                              void* d_out, int out_size, void* d_ws, size_t ws_size,
                              hipStream_t stream) {
  const float* src   = (const float*)d_in[0];
  const float* dst   = (const float*)d_in[1];
  const float* ea    = (const float*)d_in[2];
  const float* u     = (const float*)d_in[3];
  const int*   batch = (const int*)d_in[4];
  const float* W1    = (const float*)d_in[5];
  const float* b1    = (const float*)d_in[6];
  const float* W2    = (const float*)d_in[7];
  const float* b2    = (const float*)d_in[8];
  float* out = (float*)d_out;
  float* Uc  = (float*)d_ws;            // G*HID fp32 = 256 KB scratch

  const int E = in_sizes[0] / HID;
  const int G = in_sizes[3] / HID;

  prep_uc<<<G, HID, 0, stream>>>(u, W1, b1, Uc);

  const int nTiles = (E + 31) / 32;
  const int grid = nTiles < 512 ? nTiles : 512;   // 2 blocks/CU resident, persistent
  edge_mlp<<<grid, 256, 0, stream>>>(src, dst, ea, batch, W1, W2, b2, Uc, out, E, nTiles);
}